// Round 1
// baseline (119.100 us; speedup 1.0000x reference)
//
#include <hip/hip_runtime.h>
#include <math.h>

// Problem constants
#define SEQ    2048
#define ROT    32
#define NTILES 2048   // (4*2048*16 rows) / 64 rows per tile

// ---------------------------------------------------------------------------
// Setup kernel: build Wp = perm( 32 * (A @ r_matrix) ), where A composes the
// 32 sequential column rotations of the reference scan.
// Column permutation folded in: Wp[:,d] = col 2d, Wp[:,32+d] = col 2d+1,
// so the main-kernel epilogue pairs (d, 32+d) instead of (2d, 2d+1).
// Grid: 16 blocks x 256 threads; each block redundantly builds A (trivial),
// then computes 4 rows of Wp with coalesced R reads.
// ---------------------------------------------------------------------------
__global__ __launch_bounds__(256) void build_w_kernel(
    const float* __restrict__ thetas,
    const float* __restrict__ theta_scale,
    const float* __restrict__ R,        // r_matrix, 64x64 row-major
    const int*   __restrict__ pairs,    // 32 x 2
    float*       __restrict__ Wp)       // out: 64x64 row-major
{
    __shared__ float A[64 * 65];        // +1 pad: conflict-free row reads
    const int t = threadIdx.x;

    #pragma unroll
    for (int i = 0; i < 16; ++i) {
        int e = i * 256 + t;
        int r = e >> 6, c = e & 63;
        A[r * 65 + c] = (r == c) ? 1.0f : 0.0f;
    }
    __syncthreads();

    if (t < 64) {
        const float ts = theta_scale[0];
        float* Ar = &A[t * 65];
        for (int k = 0; k < ROT; ++k) {
            int i = pairs[2 * k], j = pairs[2 * k + 1];
            float th = thetas[k] * ts;
            float c = cosf(th), s = sinf(th);
            float ai = Ar[i], aj = Ar[j];
            if (i != j) { Ar[i] = c * ai + s * aj; Ar[j] = c * aj - s * ai; }
            else        { Ar[i] = s * ai; }     // ref: set(ni) then overwritten by set(nj)=xi*s
        }
    }
    __syncthreads();

    // W[r][c] = sum_k A[r][k] * R[k][c]; fold *sqrt(1024)=32 and permutation.
    const int r = (blockIdx.x << 2) + (t >> 6);   // 16 blocks * 4 rows
    const int c = t & 63;                          // coalesced over R
    const float* Ar = &A[r * 65];                  // wave-uniform -> LDS broadcast
    float acc = 0.0f;
    #pragma unroll 8
    for (int k = 0; k < 64; ++k)
        acc = fmaf(Ar[k], R[k * 64 + c], acc);
    const int dest = (c & 1) ? (32 + (c >> 1)) : (c >> 1);
    Wp[r * 64 + dest] = 32.0f * acc;
}

// ---------------------------------------------------------------------------
// Main kernel: one block per 64-row tile (rows contiguous in memory).
//   y = x_row @ Wp   (64x64, fp32 vector FMA)
//   out[d]    = y[d]*cos - y[32+d]*sin
//   out[32+d] = y[d]*sin + y[32+d]*cos     (cos/sin from position s = row/16 mod SEQ)
// LDS: Xs padded stride 65 (2-way bank alias = free); Ws read wave-uniform
// (broadcast); Y round-trips through LDS so stores are coalesced.
// ---------------------------------------------------------------------------
__global__ __launch_bounds__(256) void rotary_main_kernel(
    const float* __restrict__ x,
    const float* __restrict__ Wp,
    const float* __restrict__ inv_freq,
    float*       __restrict__ out)
{
    __shared__ float  Xs[64 * 65];
    __shared__ float  Ws[64 * 64];
    __shared__ float2 SC[4 * 32];      // cos/sin for this tile's 4 positions

    const int T    = blockIdx.x;
    const int t    = threadIdx.x;
    const int lane = t & 63;

    // ---- stage X tile (coalesced float4 global, scalar LDS writes) ----
    const float4* xg = (const float4*)(x + (size_t)T * 4096);
    #pragma unroll
    for (int i = 0; i < 4; ++i) {
        int g = i * 256 + t;           // 1024 float4s
        float4 v = xg[g];
        int row = g >> 4;              // 16 float4 per row
        int col = (g & 15) << 2;
        float* p = &Xs[row * 65 + col];
        p[0] = v.x; p[1] = v.y; p[2] = v.z; p[3] = v.w;
    }
    // ---- stage W (unpadded; only read at uniform addresses) ----
    {
        const float4* wg  = (const float4*)Wp;
        float4*       ws4 = (float4*)Ws;
        #pragma unroll
        for (int i = 0; i < 4; ++i) {
            int g = i * 256 + t;
            ws4[g] = wg[g];
        }
    }
    // ---- sincos for the 4 positions covered by this tile ----
    if (t < 128) {
        int pp = t >> 5, d = t & 31;
        int pos = (T * 4 + pp) & (SEQ - 1);    // position = (global_row/16) mod SEQ
        float ang = (float)pos * inv_freq[d];
        float sv, cv;
        sincosf(ang, &sv, &cv);
        SC[t] = make_float2(cv, sv);
    }
    __syncthreads();

    // ---- y = x_row @ Wp : wave cq computes columns [16cq, 16cq+16) for all 64 rows ----
    const int cq = __builtin_amdgcn_readfirstlane(t >> 6);
    const float* xr = &Xs[lane * 65];
    const float* wc = &Ws[cq * 16];

    float acc[16];
    #pragma unroll
    for (int m = 0; m < 16; ++m) acc[m] = 0.0f;

    #pragma unroll 8
    for (int k = 0; k < 64; ++k) {
        float xv = xr[k];                                  // 2-way bank alias: free
        const float4 w0 = *(const float4*)(wc + k * 64);   // wave-uniform: broadcast
        const float4 w1 = *(const float4*)(wc + k * 64 + 4);
        const float4 w2 = *(const float4*)(wc + k * 64 + 8);
        const float4 w3 = *(const float4*)(wc + k * 64 + 12);
        acc[ 0] = fmaf(xv, w0.x, acc[ 0]);
        acc[ 1] = fmaf(xv, w0.y, acc[ 1]);
        acc[ 2] = fmaf(xv, w0.z, acc[ 2]);
        acc[ 3] = fmaf(xv, w0.w, acc[ 3]);
        acc[ 4] = fmaf(xv, w1.x, acc[ 4]);
        acc[ 5] = fmaf(xv, w1.y, acc[ 5]);
        acc[ 6] = fmaf(xv, w1.z, acc[ 6]);
        acc[ 7] = fmaf(xv, w1.w, acc[ 7]);
        acc[ 8] = fmaf(xv, w2.x, acc[ 8]);
        acc[ 9] = fmaf(xv, w2.y, acc[ 9]);
        acc[10] = fmaf(xv, w2.z, acc[10]);
        acc[11] = fmaf(xv, w2.w, acc[11]);
        acc[12] = fmaf(xv, w3.x, acc[12]);
        acc[13] = fmaf(xv, w3.y, acc[13]);
        acc[14] = fmaf(xv, w3.z, acc[14]);
        acc[15] = fmaf(xv, w3.w, acc[15]);
    }

    __syncthreads();                       // all Xs reads done before overwrite
    #pragma unroll
    for (int m = 0; m < 16; ++m)
        Xs[lane * 65 + cq * 16 + m] = acc[m];   // reuse Xs as Y buffer
    __syncthreads();

    // ---- RoPE epilogue, perfectly coalesced stores ----
    float* og = out + (size_t)T * 4096;
    const int w = t >> 6;
    #pragma unroll
    for (int u = 0; u < 16; ++u) {
        int row = u * 4 + w;               // wave-uniform
        int d   = lane & 31;
        float yd = Xs[row * 65 + d];       // broadcast pairs (lane, lane+32)
        float y2 = Xs[row * 65 + 32 + d];
        float2 cs = SC[(row >> 4) * 32 + d];
        float o = (lane < 32) ? (yd * cs.x - y2 * cs.y)
                              : (yd * cs.y + y2 * cs.x);
        og[u * 256 + t] = o;               // consecutive lanes, consecutive addrs
    }
}

extern "C" void kernel_launch(void* const* d_in, const int* in_sizes, int n_in,
                              void* d_out, int out_size, void* d_ws, size_t ws_size,
                              hipStream_t stream) {
    const float* x           = (const float*)d_in[0];
    const float* thetas      = (const float*)d_in[1];
    const float* theta_scale = (const float*)d_in[2];
    const float* r_matrix    = (const float*)d_in[3];
    const float* inv_freq    = (const float*)d_in[4];
    const int*   pairs       = (const int*)d_in[5];
    float*       out         = (float*)d_out;
    float*       Wp          = (float*)d_ws;   // 64*64 floats = 16 KB scratch

    build_w_kernel<<<16, 256, 0, stream>>>(thetas, theta_scale, r_matrix, pairs, Wp);
    rotary_main_kernel<<<NTILES, 256, 0, stream>>>(x, Wp, inv_freq, out);
}

// Round 3
// 112.690 us; speedup vs baseline: 1.0569x; 1.0569x over previous
//
#include <hip/hip_runtime.h>
#include <math.h>

// Problem constants
#define SEQ    2048
#define ROT    32
#define ROWS_PER_BLOCK 128
#define NTILES (131072 / ROWS_PER_BLOCK)   // 4*2048*16 rows / 128 = 1024 blocks

// ---------------------------------------------------------------------------
// Setup kernel: W = 32 * (A @ r_matrix), where A composes the 32 sequential
// column rotations of the reference scan (xx_new = xx @ E_k, A = E_0..E_31).
// ---------------------------------------------------------------------------
__global__ __launch_bounds__(256) void build_w_kernel(
    const float* __restrict__ thetas,
    const float* __restrict__ theta_scale,
    const float* __restrict__ R,        // r_matrix, 64x64 row-major
    const int*   __restrict__ pairs,    // 32 x 2
    float*       __restrict__ W)        // out: 64x64 row-major
{
    __shared__ float A[64 * 65];        // +1 pad: conflict-free row reads
    const int t = threadIdx.x;

    #pragma unroll
    for (int i = 0; i < 16; ++i) {
        int e = i * 256 + t;
        int r = e >> 6, c = e & 63;
        A[r * 65 + c] = (r == c) ? 1.0f : 0.0f;
    }
    __syncthreads();

    if (t < 64) {
        const float ts = theta_scale[0];
        float* Ar = &A[t * 65];
        for (int k = 0; k < ROT; ++k) {
            int i = pairs[2 * k], j = pairs[2 * k + 1];
            float th = thetas[k] * ts;
            float c = cosf(th), s = sinf(th);
            float ai = Ar[i], aj = Ar[j];
            if (i != j) { Ar[i] = c * ai + s * aj; Ar[j] = c * aj - s * ai; }
            else        { Ar[i] = s * ai; }   // ref: set(ni) overwritten by set(nj)=xi*s
        }
    }
    __syncthreads();

    const int r = (blockIdx.x << 2) + (t >> 6);   // 16 blocks * 4 rows
    const int c = t & 63;                          // coalesced over R
    const float* Ar = &A[r * 65];                  // wave-uniform -> LDS broadcast
    float acc = 0.0f;
    #pragma unroll 8
    for (int k = 0; k < 64; ++k)
        acc = fmaf(Ar[k], R[k * 64 + c], acc);
    W[r * 64 + c] = 32.0f * acc;                   // fold *sqrt(1024)
}

// ---------------------------------------------------------------------------
// Main kernel: 128 rows/block, 256 threads. Thread (rg = t>>3, cg = t&7)
// computes a 4-row x 8-col register tile of y = x_row @ W, then applies the
// RoPE 2x2 rotation in registers (cols 2d/2d+1 -> out d / 32+d) and stores
// two aligned float4 per row (full 128B cache lines per wave instr).
//
// LDS layouts:
//   Xt[k][row] transposed, XOR-swizzled in 16B chunks:
//     addr(k,row) = k*128 + (((row>>2) ^ (k&31))<<2) + (row&3)
//     -> k-loop b128 reads: 8 distinct bank-quads/instr, broadcast x8  (free)
//     -> staging b32 writes: 2-way bank alias                          (free)
//   Ws[k][c] row-major unpadded: b128 reads broadcast x8, 2-phase      (cheap)
// ---------------------------------------------------------------------------
__global__ __launch_bounds__(256) void rotary_main_kernel(
    const float* __restrict__ x,
    const float* __restrict__ W,
    const float* __restrict__ inv_freq,
    float*       __restrict__ out)
{
    __shared__ float Xt[64 * 128];     // 32 KB
    __shared__ float Ws[64 * 64];      // 16 KB
    __shared__ float SCc[8 * 32];      // cos per (pos-group, d)
    __shared__ float SCs[8 * 32];      // sin per (pos-group, d)

    const int T = blockIdx.x;
    const int t = threadIdx.x;

    // ---- stage X tile: coalesced float4 global reads, swizzled LDS scatter ----
    const float4* xg = (const float4*)(x + (size_t)T * (ROWS_PER_BLOCK * 64));
    #pragma unroll
    for (int it = 0; it < 8; ++it) {
        int g = it * 256 + t;          // 2048 float4s
        float4 v = xg[g];
        int row = g >> 4;              // 16 float4 per row
        int k4  = (g & 15) << 2;
        float vv[4] = {v.x, v.y, v.z, v.w};
        #pragma unroll
        for (int j = 0; j < 4; ++j) {
            int k = k4 + j;
            Xt[k * 128 + (((row >> 2) ^ (k & 31)) << 2) + (row & 3)] = vv[j];
        }
    }
    // ---- stage W: 4096 floats = 1024 float4 -> 4 iterations of 256 threads ----
    {
        const float4* wg  = (const float4*)W;
        float4*       ws4 = (float4*)Ws;
        #pragma unroll
        for (int i = 0; i < 4; ++i)
            ws4[i * 256 + t] = wg[i * 256 + t];
    }
    // ---- sincos for the 8 positions covered by this tile ----
    {
        int pg = t >> 5, d = t & 31;
        int pos = (T * 8 + pg) & (SEQ - 1);   // position = global_row/16 mod SEQ
        float sv, cv;
        sincosf((float)pos * inv_freq[d], &sv, &cv);
        SCc[t] = cv;
        SCs[t] = sv;
    }
    __syncthreads();

    // ---- register-tile matmul: acc[m][j] = y[rg*4+m][cg*8+j] ----
    const int rg = t >> 3;             // 0..31 (8 distinct per wave)
    const int cg = t & 7;              // 0..7

    float acc[4][8];
    #pragma unroll
    for (int m = 0; m < 4; ++m)
        #pragma unroll
        for (int j = 0; j < 8; ++j) acc[m][j] = 0.0f;

    #pragma unroll 4
    for (int k = 0; k < 64; ++k) {
        const float4 xv = *(const float4*)&Xt[k * 128 + ((rg ^ (k & 31)) << 2)];
        const float4 w0 = *(const float4*)&Ws[k * 64 + cg * 8];
        const float4 w1 = *(const float4*)&Ws[k * 64 + cg * 8 + 4];
        const float xs[4] = {xv.x, xv.y, xv.z, xv.w};
        const float ws[8] = {w0.x, w0.y, w0.z, w0.w, w1.x, w1.y, w1.z, w1.w};
        #pragma unroll
        for (int m = 0; m < 4; ++m)
            #pragma unroll
            for (int j = 0; j < 8; ++j)
                acc[m][j] = fmaf(xs[m], ws[j], acc[m][j]);
    }

    // ---- RoPE epilogue in registers; coalesced 16B stores ----
    const int scb = (rg >> 2) * 32 + cg * 4;     // pos-group base (uniform per thread)
    const float4 cv = *(const float4*)&SCc[scb];
    const float4 sv = *(const float4*)&SCs[scb];
    const float cs4[4] = {cv.x, cv.y, cv.z, cv.w};
    const float sn4[4] = {sv.x, sv.y, sv.z, sv.w};

    float* og = out + (size_t)T * (ROWS_PER_BLOCK * 64);
    #pragma unroll
    for (int m = 0; m < 4; ++m) {
        int row = rg * 4 + m;
        float o1[4], o2[4];
        #pragma unroll
        for (int d = 0; d < 4; ++d) {
            float a = acc[m][2 * d];       // even col  -> x1
            float b = acc[m][2 * d + 1];   // odd col   -> x2
            o1[d] = a * cs4[d] - b * sn4[d];
            o2[d] = a * sn4[d] + b * cs4[d];
        }
        *(float4*)&og[row * 64 + cg * 4]      = make_float4(o1[0], o1[1], o1[2], o1[3]);
        *(float4*)&og[row * 64 + 32 + cg * 4] = make_float4(o2[0], o2[1], o2[2], o2[3]);
    }
}

extern "C" void kernel_launch(void* const* d_in, const int* in_sizes, int n_in,
                              void* d_out, int out_size, void* d_ws, size_t ws_size,
                              hipStream_t stream) {
    const float* x           = (const float*)d_in[0];
    const float* thetas      = (const float*)d_in[1];
    const float* theta_scale = (const float*)d_in[2];
    const float* r_matrix    = (const float*)d_in[3];
    const float* inv_freq    = (const float*)d_in[4];
    const int*   pairs       = (const int*)d_in[5];
    float*       out         = (float*)d_out;
    float*       W           = (float*)d_ws;   // 64*64 floats = 16 KB scratch

    build_w_kernel<<<16, 256, 0, stream>>>(thetas, theta_scale, r_matrix, pairs, W);
    rotary_main_kernel<<<NTILES, 256, 0, stream>>>(x, W, inv_freq, out);
}

// Round 4
// 112.412 us; speedup vs baseline: 1.0595x; 1.0025x over previous
//
#include <hip/hip_runtime.h>
#include <math.h>

// Problem constants
#define SEQ    2048
#define ROT    32
#define ROWS_PER_BLOCK 128
#define NTILES (131072 / ROWS_PER_BLOCK)   // 1024 blocks

#define AS1 __attribute__((address_space(1)))
#define AS3 __attribute__((address_space(3)))

// ---------------------------------------------------------------------------
// Setup kernel: W = 32 * (A @ r_matrix), where A composes the 32 sequential
// column rotations of the reference scan (x <- x @ E_k, A = E_0 ... E_31).
// ---------------------------------------------------------------------------
__global__ __launch_bounds__(256) void build_w_kernel(
    const float* __restrict__ thetas,
    const float* __restrict__ theta_scale,
    const float* __restrict__ R,        // r_matrix, 64x64 row-major
    const int*   __restrict__ pairs,    // 32 x 2
    float*       __restrict__ W)        // out: 64x64 row-major
{
    __shared__ float A[64 * 65];        // +1 pad: conflict-free row reads
    const int t = threadIdx.x;

    #pragma unroll
    for (int i = 0; i < 16; ++i) {
        int e = i * 256 + t;
        int r = e >> 6, c = e & 63;
        A[r * 65 + c] = (r == c) ? 1.0f : 0.0f;
    }
    __syncthreads();

    if (t < 64) {
        const float ts = theta_scale[0];
        float* Ar = &A[t * 65];
        for (int k = 0; k < ROT; ++k) {
            int i = pairs[2 * k], j = pairs[2 * k + 1];
            float th = thetas[k] * ts;
            float c = cosf(th), s = sinf(th);
            float ai = Ar[i], aj = Ar[j];
            if (i != j) { Ar[i] = c * ai + s * aj; Ar[j] = c * aj - s * ai; }
            else        { Ar[i] = s * ai; }   // ref: set(ni) overwritten by set(nj)=xi*s
        }
    }
    __syncthreads();

    const int r = (blockIdx.x << 2) + (t >> 6);   // 16 blocks * 4 rows
    const int c = t & 63;                          // coalesced over R
    const float* Ar = &A[r * 65];                  // wave-uniform -> LDS broadcast
    float acc = 0.0f;
    #pragma unroll 8
    for (int k = 0; k < 64; ++k)
        acc = fmaf(Ar[k], R[k * 64 + c], acc);
    W[r * 64 + c] = 32.0f * acc;                   // fold *sqrt(1024)
}

// ---------------------------------------------------------------------------
// Main kernel: 128 rows/block, 256 threads. Thread (rg=t>>3, cg=t&7) computes
// a 4-row x 8-col register tile of y = x_row @ W, applies the RoPE 2x2
// rotation in registers (cols 2d/2d+1 -> out d / 32+d), stores 2 float4/row.
//
// Staging via global_load_lds (16B, no VGPR round-trip, no ds_writes).
// LDS dst is forced to base+lane*16, so the conflict swizzle is applied to
// the GLOBAL SOURCE index instead of the LDS destination:
//   Xs layout: float addr = row*64 + 4*(q ^ (rg&7)) + e   (rg = row>>2)
//   staging lane l, region ri (4 rows): loads global chunk (l&15) ^ (ri&7)
//     -> contiguous 256B per 16-lane group: coalescing intact
//   k-loop b128 X read: bank-group (kk ^ rg) % 8, distinct per row-group
//     -> conflict-free.  Ws unswizzled (same read pattern as prior round).
// ---------------------------------------------------------------------------
__global__ __launch_bounds__(256) void rotary_main_kernel(
    const float* __restrict__ x,
    const float* __restrict__ W,
    const float* __restrict__ inv_freq,
    float*       __restrict__ out)
{
    __shared__ float Xs[128 * 64];     // 32 KB, row-major chunk-swizzled
    __shared__ float Ws[64 * 64];      // 16 KB, row-major
    __shared__ float SCc[8 * 32];      // cos per (pos-group, d)
    __shared__ float SCs[8 * 32];      // sin per (pos-group, d)

    const int T    = blockIdx.x;
    const int t    = threadIdx.x;
    const int wave = t >> 6;
    const int lane = t & 63;

    const float* xg = x + (size_t)T * (ROWS_PER_BLOCK * 64);

    // ---- stage X: 32 regions of 1KB (4 rows each); 4 waves x 8 iters ----
    #pragma unroll
    for (int i = 0; i < 8; ++i) {
        int ri  = i * 4 + wave;              // region 0..31 -> rows 4ri..4ri+3
        int row = ri * 4 + (lane >> 4);
        int q   = (lane & 15) ^ (ri & 7);    // global 16B chunk (swizzle inverse)
        const float* gp = xg + row * 64 + q * 4;
        __builtin_amdgcn_global_load_lds((const AS1 unsigned int*)gp,
                                         (AS3 unsigned int*)&Xs[ri * 256], 16, 0, 0);
    }
    // ---- stage W: 16 regions of 1KB; 4 waves x 4 iters, no swizzle ----
    #pragma unroll
    for (int i = 0; i < 4; ++i) {
        int ri  = i * 4 + wave;              // region 0..15 -> rows 4ri..4ri+3
        int row = ri * 4 + (lane >> 4);
        const float* gp = W + row * 64 + (lane & 15) * 4;
        __builtin_amdgcn_global_load_lds((const AS1 unsigned int*)gp,
                                         (AS3 unsigned int*)&Ws[ri * 256], 16, 0, 0);
    }
    // ---- sincos for the 8 positions covered by this tile ----
    {
        int pg = t >> 5, d = t & 31;
        int pos = (T * 8 + pg) & (SEQ - 1);  // position = global_row/16 mod SEQ
        float sv, cv;
        sincosf((float)pos * inv_freq[d], &sv, &cv);
        SCc[t] = cv;
        SCs[t] = sv;
    }
    __syncthreads();

    // ---- register-tile matmul: acc[m][j] = y[rg*4+m][cg*8+j] ----
    const int rg = t >> 3;             // 0..31
    const int cg = t & 7;              // 0..7

    float acc[4][8];
    #pragma unroll
    for (int m = 0; m < 4; ++m)
        #pragma unroll
        for (int j = 0; j < 8; ++j) acc[m][j] = 0.0f;

    const int xslot = (rg & 7);        // row-group swizzle key
    #pragma unroll 2
    for (int kk = 0; kk < 16; ++kk) {  // 4 k per iteration
        float4 xv[4];
        #pragma unroll
        for (int m = 0; m < 4; ++m)
            xv[m] = *(const float4*)&Xs[(rg * 4 + m) * 64 + ((kk ^ xslot) << 2)];
        float4 wv[8];
        #pragma unroll
        for (int r = 0; r < 4; ++r) {
            wv[2 * r]     = *(const float4*)&Ws[(4 * kk + r) * 64 + cg * 8];
            wv[2 * r + 1] = *(const float4*)&Ws[(4 * kk + r) * 64 + cg * 8 + 4];
        }
        #pragma unroll
        for (int m = 0; m < 4; ++m) {
            const float xs4[4] = {xv[m].x, xv[m].y, xv[m].z, xv[m].w};
            #pragma unroll
            for (int r = 0; r < 4; ++r) {
                const float4 w0 = wv[2 * r], w1 = wv[2 * r + 1];
                acc[m][0] = fmaf(xs4[r], w0.x, acc[m][0]);
                acc[m][1] = fmaf(xs4[r], w0.y, acc[m][1]);
                acc[m][2] = fmaf(xs4[r], w0.z, acc[m][2]);
                acc[m][3] = fmaf(xs4[r], w0.w, acc[m][3]);
                acc[m][4] = fmaf(xs4[r], w1.x, acc[m][4]);
                acc[m][5] = fmaf(xs4[r], w1.y, acc[m][5]);
                acc[m][6] = fmaf(xs4[r], w1.z, acc[m][6]);
                acc[m][7] = fmaf(xs4[r], w1.w, acc[m][7]);
            }
        }
    }

    // ---- RoPE epilogue in registers; coalesced 16B stores ----
    const int scb = (rg >> 2) * 32 + cg * 4;     // pos-group base
    const float4 cv = *(const float4*)&SCc[scb];
    const float4 sv = *(const float4*)&SCs[scb];
    const float cs4[4] = {cv.x, cv.y, cv.z, cv.w};
    const float sn4[4] = {sv.x, sv.y, sv.z, sv.w};

    float* og = out + (size_t)T * (ROWS_PER_BLOCK * 64);
    #pragma unroll
    for (int m = 0; m < 4; ++m) {
        int row = rg * 4 + m;
        float o1[4], o2[4];
        #pragma unroll
        for (int d = 0; d < 4; ++d) {
            float a = acc[m][2 * d];       // even col -> x1
            float b = acc[m][2 * d + 1];   // odd col  -> x2
            o1[d] = a * cs4[d] - b * sn4[d];
            o2[d] = a * sn4[d] + b * cs4[d];
        }
        *(float4*)&og[row * 64 + cg * 4]      = make_float4(o1[0], o1[1], o1[2], o1[3]);
        *(float4*)&og[row * 64 + 32 + cg * 4] = make_float4(o2[0], o2[1], o2[2], o2[3]);
    }
}

extern "C" void kernel_launch(void* const* d_in, const int* in_sizes, int n_in,
                              void* d_out, int out_size, void* d_ws, size_t ws_size,
                              hipStream_t stream) {
    const float* x           = (const float*)d_in[0];
    const float* thetas      = (const float*)d_in[1];
    const float* theta_scale = (const float*)d_in[2];
    const float* r_matrix    = (const float*)d_in[3];
    const float* inv_freq    = (const float*)d_in[4];
    const int*   pairs       = (const int*)d_in[5];
    float*       out         = (float*)d_out;
    float*       W           = (float*)d_ws;   // 64*64 floats = 16 KB scratch

    build_w_kernel<<<16, 256, 0, stream>>>(thetas, theta_scale, r_matrix, pairs, W);
    rotary_main_kernel<<<NTILES, 256, 0, stream>>>(x, W, inv_freq, out);
}

// Round 5
// 110.275 us; speedup vs baseline: 1.0800x; 1.0194x over previous
//
#include <hip/hip_runtime.h>
#include <math.h>

// Problem constants
#define SEQ    2048
#define ROT    32
#define ROWS_PER_BLOCK 64
#define NTILES (131072 / ROWS_PER_BLOCK)   // 2048 blocks

#define AS1 __attribute__((address_space(1)))
#define AS3 __attribute__((address_space(3)))

// ---------------------------------------------------------------------------
// Setup kernel: W = 32 * (A @ r_matrix), where A composes the 32 sequential
// column rotations of the reference scan (x <- x @ E_k, A = E_0 ... E_31).
// v2: hoist sincos + pairs out of the sequential scan so the 32-step chain
// is pure in-order LDS RMW (no global-load / transcendental in the chain).
// ---------------------------------------------------------------------------
__global__ __launch_bounds__(256) void build_w_kernel(
    const float* __restrict__ thetas,
    const float* __restrict__ theta_scale,
    const float* __restrict__ R,        // r_matrix, 64x64 row-major
    const int*   __restrict__ pairs,    // 32 x 2
    float*       __restrict__ W)        // out: 64x64 row-major
{
    __shared__ float A[64 * 65];        // +1 pad: conflict-free row reads
    __shared__ float Cs[ROT], Ss[ROT];
    __shared__ int   Pi[ROT], Pj[ROT];
    const int t = threadIdx.x;

    #pragma unroll
    for (int i = 0; i < 16; ++i) {
        int e = i * 256 + t;
        int r = e >> 6, c = e & 63;
        A[r * 65 + c] = (r == c) ? 1.0f : 0.0f;
    }
    if (t < ROT) {                      // precompute rotation params
        float th = thetas[t] * theta_scale[0];
        float sv, cv;
        sincosf(th, &sv, &cv);
        Cs[t] = cv; Ss[t] = sv;
        Pi[t] = pairs[2 * t]; Pj[t] = pairs[2 * t + 1];
    }
    __syncthreads();

    if (t < 64) {                       // 32-step sequential scan, pure LDS
        float* Ar = &A[t * 65];
        for (int k = 0; k < ROT; ++k) {
            int i = Pi[k], j = Pj[k];
            float c = Cs[k], s = Ss[k];
            float ai = Ar[i], aj = Ar[j];
            if (i != j) { Ar[i] = c * ai + s * aj; Ar[j] = c * aj - s * ai; }
            else        { Ar[i] = s * ai; }   // ref: set(ni) overwritten by set(nj)=xi*s
        }
    }
    __syncthreads();

    const int r = (blockIdx.x << 2) + (t >> 6);   // 16 blocks * 4 rows
    const int c = t & 63;                          // coalesced over R
    const float* Ar = &A[r * 65];                  // wave-uniform -> LDS broadcast
    float acc = 0.0f;
    #pragma unroll 8
    for (int k = 0; k < 64; ++k)
        acc = fmaf(Ar[k], R[k * 64 + c], acc);
    W[r * 64 + c] = 32.0f * acc;                   // fold *sqrt(1024)
}

// ---------------------------------------------------------------------------
// Main kernel: 64 rows/block (2048 blocks), 256 threads, ~33 KB LDS
// -> 4 blocks/CU residency (was 3 at 128 rows/50 KB).
// Thread (rp=t>>3, cg=t&7) computes a 2-row x 8-col register tile of
// y = x_row @ W, applies RoPE in registers (cols 2d/2d+1 -> out d / 32+d),
// stores 2 float4 per row.
//
// Staging via global_load_lds (16B); conflict swizzle applied to the GLOBAL
// source index (LDS dst is forced to base+lane*16):
//   Xs float addr = row*64 + 4*(q ^ ((row>>2)&7)) + e
//   staging lane l, region ri (4 rows): global chunk (l&15) ^ (ri&7)
//   k-loop b128 X read: bank-quad (kk ^ (row>>2)) & 7 -> worst 2-way (free)
//   Ws unswizzled: b128 reads at cg*8 -> 2-way (free), broadcast x8
// ---------------------------------------------------------------------------
__global__ __launch_bounds__(256) void rotary_main_kernel(
    const float* __restrict__ x,
    const float* __restrict__ W,
    const float* __restrict__ inv_freq,
    float*       __restrict__ out)
{
    __shared__ float Xs[64 * 64];      // 16 KB, chunk-swizzled
    __shared__ float Ws[64 * 64];      // 16 KB
    __shared__ float SCc[4 * 32];      // cos per (pos-group, d)
    __shared__ float SCs[4 * 32];      // sin per (pos-group, d)

    const int T    = blockIdx.x;
    const int t    = threadIdx.x;
    const int wave = t >> 6;
    const int lane = t & 63;

    const float* xg = x + (size_t)T * (ROWS_PER_BLOCK * 64);

    // ---- stage X: 16 regions of 1KB (4 rows each); 4 waves x 4 iters ----
    #pragma unroll
    for (int i = 0; i < 4; ++i) {
        int ri  = i * 4 + wave;              // region 0..15 -> rows 4ri..4ri+3
        int row = ri * 4 + (lane >> 4);
        int q   = (lane & 15) ^ (ri & 7);    // swizzle inverse on global chunk
        const float* gp = xg + row * 64 + q * 4;
        __builtin_amdgcn_global_load_lds((const AS1 unsigned int*)gp,
                                         (AS3 unsigned int*)&Xs[ri * 256], 16, 0, 0);
    }
    // ---- stage W: 16 regions of 1KB; no swizzle ----
    #pragma unroll
    for (int i = 0; i < 4; ++i) {
        int ri  = i * 4 + wave;
        int row = ri * 4 + (lane >> 4);
        const float* gp = W + row * 64 + (lane & 15) * 4;
        __builtin_amdgcn_global_load_lds((const AS1 unsigned int*)gp,
                                         (AS3 unsigned int*)&Ws[ri * 256], 16, 0, 0);
    }
    // ---- sincos for the 4 positions covered by this tile ----
    if (t < 128) {
        int pg = t >> 5, d = t & 31;
        int pos = (T * 4 + pg) & (SEQ - 1);  // position = global_row/16 mod SEQ
        float sv, cv;
        sincosf((float)pos * inv_freq[d], &sv, &cv);
        SCc[t] = cv;
        SCs[t] = sv;
    }
    __syncthreads();

    // ---- register-tile matmul: acc[m][j] = y[rp*2+m][cg*8+j] ----
    const int rp = t >> 3;             // 0..31 -> rows 2rp, 2rp+1
    const int cg = t & 7;              // 0..7

    float acc[2][8];
    #pragma unroll
    for (int m = 0; m < 2; ++m)
        #pragma unroll
        for (int j = 0; j < 8; ++j) acc[m][j] = 0.0f;

    const int r0 = rp * 2;
    const int s0 = (r0 >> 2) & 7;      // swizzle key (same for both rows)
    #pragma unroll 4
    for (int kk = 0; kk < 16; ++kk) {  // 4 k per iteration
        const float4 xv0 = *(const float4*)&Xs[ r0      * 64 + ((kk ^ s0) << 2)];
        const float4 xv1 = *(const float4*)&Xs[(r0 + 1) * 64 + ((kk ^ s0) << 2)];
        float4 wv[8];
        #pragma unroll
        for (int r = 0; r < 4; ++r) {
            wv[2 * r]     = *(const float4*)&Ws[(4 * kk + r) * 64 + cg * 8];
            wv[2 * r + 1] = *(const float4*)&Ws[(4 * kk + r) * 64 + cg * 8 + 4];
        }
        const float xa[2][4] = {{xv0.x, xv0.y, xv0.z, xv0.w},
                                {xv1.x, xv1.y, xv1.z, xv1.w}};
        #pragma unroll
        for (int m = 0; m < 2; ++m)
            #pragma unroll
            for (int r = 0; r < 4; ++r) {
                const float4 w0 = wv[2 * r], w1 = wv[2 * r + 1];
                const float xs = xa[m][r];
                acc[m][0] = fmaf(xs, w0.x, acc[m][0]);
                acc[m][1] = fmaf(xs, w0.y, acc[m][1]);
                acc[m][2] = fmaf(xs, w0.z, acc[m][2]);
                acc[m][3] = fmaf(xs, w0.w, acc[m][3]);
                acc[m][4] = fmaf(xs, w1.x, acc[m][4]);
                acc[m][5] = fmaf(xs, w1.y, acc[m][5]);
                acc[m][6] = fmaf(xs, w1.z, acc[m][6]);
                acc[m][7] = fmaf(xs, w1.w, acc[m][7]);
            }
    }

    // ---- RoPE epilogue in registers; coalesced 16B stores ----
    const int scb = (r0 >> 4) * 32 + cg * 4;   // pos-group (uniform: r0 even,
    const float4 cv = *(const float4*)&SCc[scb];  // r0+1 never crosses 16-row bdy)
    const float4 sv = *(const float4*)&SCs[scb];
    const float cs4[4] = {cv.x, cv.y, cv.z, cv.w};
    const float sn4[4] = {sv.x, sv.y, sv.z, sv.w};

    float* og = out + (size_t)T * (ROWS_PER_BLOCK * 64);
    #pragma unroll
    for (int m = 0; m < 2; ++m) {
        int row = r0 + m;
        float o1[4], o2[4];
        #pragma unroll
        for (int d = 0; d < 4; ++d) {
            float a = acc[m][2 * d];       // even col -> x1
            float b = acc[m][2 * d + 1];   // odd col  -> x2
            o1[d] = a * cs4[d] - b * sn4[d];
            o2[d] = a * sn4[d] + b * cs4[d];
        }
        *(float4*)&og[row * 64 + cg * 4]      = make_float4(o1[0], o1[1], o1[2], o1[3]);
        *(float4*)&og[row * 64 + 32 + cg * 4] = make_float4(o2[0], o2[1], o2[2], o2[3]);
    }
}

extern "C" void kernel_launch(void* const* d_in, const int* in_sizes, int n_in,
                              void* d_out, int out_size, void* d_ws, size_t ws_size,
                              hipStream_t stream) {
    const float* x           = (const float*)d_in[0];
    const float* thetas      = (const float*)d_in[1];
    const float* theta_scale = (const float*)d_in[2];
    const float* r_matrix    = (const float*)d_in[3];
    const float* inv_freq    = (const float*)d_in[4];
    const int*   pairs       = (const int*)d_in[5];
    float*       out         = (float*)d_out;
    float*       W           = (float*)d_ws;   // 64*64 floats = 16 KB scratch

    build_w_kernel<<<16, 256, 0, stream>>>(thetas, theta_scale, r_matrix, pairs, W);
    rotary_main_kernel<<<NTILES, 256, 0, stream>>>(x, W, inv_freq, out);
}

// Round 6
// 109.163 us; speedup vs baseline: 1.0910x; 1.0102x over previous
//
#include <hip/hip_runtime.h>
#include <math.h>

// Problem constants
#define SEQ    2048
#define ROT    32
#define ROWS_PER_BLOCK 64
#define NTILES (131072 / ROWS_PER_BLOCK)   // 2048 blocks

#define AS1 __attribute__((address_space(1)))
#define AS3 __attribute__((address_space(3)))

// ---------------------------------------------------------------------------
// Setup kernel: W = 32 * (A @ r_matrix), where A composes the 32 sequential
// column rotations of the reference scan (x <- x @ E_k, A = E_0 ... E_31).
// sincos/pairs hoisted out of the scan: the 32-step chain is pure LDS RMW.
// ---------------------------------------------------------------------------
__global__ __launch_bounds__(256) void build_w_kernel(
    const float* __restrict__ thetas,
    const float* __restrict__ theta_scale,
    const float* __restrict__ R,        // r_matrix, 64x64 row-major
    const int*   __restrict__ pairs,    // 32 x 2
    float*       __restrict__ W)        // out: 64x64 row-major
{
    __shared__ float A[64 * 65];        // +1 pad: conflict-free row reads
    __shared__ float Cs[ROT], Ss[ROT];
    __shared__ int   Pi[ROT], Pj[ROT];
    const int t = threadIdx.x;

    #pragma unroll
    for (int i = 0; i < 16; ++i) {
        int e = i * 256 + t;
        int r = e >> 6, c = e & 63;
        A[r * 65 + c] = (r == c) ? 1.0f : 0.0f;
    }
    if (t < ROT) {                      // precompute rotation params
        float th = thetas[t] * theta_scale[0];
        float sv, cv;
        sincosf(th, &sv, &cv);
        Cs[t] = cv; Ss[t] = sv;
        Pi[t] = pairs[2 * t]; Pj[t] = pairs[2 * t + 1];
    }
    __syncthreads();

    if (t < 64) {                       // 32-step sequential scan, pure LDS
        float* Ar = &A[t * 65];
        for (int k = 0; k < ROT; ++k) {
            int i = Pi[k], j = Pj[k];
            float c = Cs[k], s = Ss[k];
            float ai = Ar[i], aj = Ar[j];
            if (i != j) { Ar[i] = c * ai + s * aj; Ar[j] = c * aj - s * ai; }
            else        { Ar[i] = s * ai; }   // ref: set(ni) overwritten by set(nj)=xi*s
        }
    }
    __syncthreads();

    const int r = (blockIdx.x << 2) + (t >> 6);   // 16 blocks * 4 rows
    const int c = t & 63;                          // coalesced over R
    const float* Ar = &A[r * 65];                  // wave-uniform -> LDS broadcast
    float acc = 0.0f;
    #pragma unroll 8
    for (int k = 0; k < 64; ++k)
        acc = fmaf(Ar[k], R[k * 64 + c], acc);
    W[r * 64 + c] = 32.0f * acc;                   // fold *sqrt(1024)
}

// ---------------------------------------------------------------------------
// Main kernel v3: 64 rows/block, 2048 blocks, 256 threads, ~17 KB LDS
// -> 7-8 blocks/CU (28-32 waves) for phase overlap (was 4 blocks at 33 KB).
//
// X is NOT LDS-staged: thread (rp=t>>3, cg=t&7) reads its 2 rows directly
// from global as float4s. Within a wave-instr the 8-way cg duplication
// dedups to 8 distinct 16B chunks (512B stride); granule remainders are
// L1 hits on neighboring kk iterations -> HBM traffic stays 33.5 MB and
// there is no X barrier. Only W (16 KB, broadcast reads) + sincos go
// through LDS, with a single __syncthreads().
// ---------------------------------------------------------------------------
__global__ __launch_bounds__(256) void rotary_main_kernel(
    const float* __restrict__ x,
    const float* __restrict__ W,
    const float* __restrict__ inv_freq,
    float*       __restrict__ out)
{
    __shared__ float Ws[64 * 64];      // 16 KB, row-major
    __shared__ float SCc[4 * 32];      // cos per (pos-group, d)
    __shared__ float SCs[4 * 32];      // sin per (pos-group, d)

    const int T    = blockIdx.x;
    const int t    = threadIdx.x;
    const int wave = t >> 6;
    const int lane = t & 63;

    // ---- stage W: 16 regions of 1KB via global_load_lds (no VGPR trip) ----
    #pragma unroll
    for (int i = 0; i < 4; ++i) {
        int ri  = i * 4 + wave;              // region 0..15 -> rows 4ri..4ri+3
        int row = ri * 4 + (lane >> 4);
        const float* gp = W + row * 64 + (lane & 15) * 4;
        __builtin_amdgcn_global_load_lds((const AS1 unsigned int*)gp,
                                         (AS3 unsigned int*)&Ws[ri * 256], 16, 0, 0);
    }
    // ---- sincos for the 4 positions covered by this tile ----
    if (t < 128) {
        int pg = t >> 5, d = t & 31;
        int pos = (T * 4 + pg) & (SEQ - 1);  // position = global_row/16 mod SEQ
        float sv, cv;
        sincosf((float)pos * inv_freq[d], &sv, &cv);
        SCc[t] = cv;
        SCs[t] = sv;
    }
    __syncthreads();

    // ---- register-tile matmul: acc[m][j] = y[rp*2+m][cg*8+j] ----
    const int rp = t >> 3;             // 0..31 -> rows 2rp, 2rp+1
    const int cg = t & 7;              // 0..7
    const int r0 = rp * 2;

    const float* xg  = x + (size_t)T * (ROWS_PER_BLOCK * 64);
    const float* xr0 = xg + r0 * 64;         // 256B-aligned row base
    const float* xr1 = xr0 + 64;

    float acc[2][8];
    #pragma unroll
    for (int m = 0; m < 2; ++m)
        #pragma unroll
        for (int j = 0; j < 8; ++j) acc[m][j] = 0.0f;

    #pragma unroll 2
    for (int kk = 0; kk < 16; ++kk) {  // 4 k per iteration
        const float4 xv0 = *(const float4*)(xr0 + (kk << 2));   // global, L1-friendly
        const float4 xv1 = *(const float4*)(xr1 + (kk << 2));
        float4 wv[8];
        #pragma unroll
        for (int r = 0; r < 4; ++r) {
            wv[2 * r]     = *(const float4*)&Ws[(4 * kk + r) * 64 + cg * 8];
            wv[2 * r + 1] = *(const float4*)&Ws[(4 * kk + r) * 64 + cg * 8 + 4];
        }
        const float xa[2][4] = {{xv0.x, xv0.y, xv0.z, xv0.w},
                                {xv1.x, xv1.y, xv1.z, xv1.w}};
        #pragma unroll
        for (int m = 0; m < 2; ++m)
            #pragma unroll
            for (int r = 0; r < 4; ++r) {
                const float4 w0 = wv[2 * r], w1 = wv[2 * r + 1];
                const float xs = xa[m][r];
                acc[m][0] = fmaf(xs, w0.x, acc[m][0]);
                acc[m][1] = fmaf(xs, w0.y, acc[m][1]);
                acc[m][2] = fmaf(xs, w0.z, acc[m][2]);
                acc[m][3] = fmaf(xs, w0.w, acc[m][3]);
                acc[m][4] = fmaf(xs, w1.x, acc[m][4]);
                acc[m][5] = fmaf(xs, w1.y, acc[m][5]);
                acc[m][6] = fmaf(xs, w1.z, acc[m][6]);
                acc[m][7] = fmaf(xs, w1.w, acc[m][7]);
            }
    }

    // ---- RoPE epilogue in registers; coalesced 16B stores ----
    const int scb = (r0 >> 4) * 32 + cg * 4;   // pos-group (r0 even: rows never
    const float4 cv = *(const float4*)&SCc[scb];  // cross a 16-row boundary)
    const float4 sv = *(const float4*)&SCs[scb];
    const float cs4[4] = {cv.x, cv.y, cv.z, cv.w};
    const float sn4[4] = {sv.x, sv.y, sv.z, sv.w};

    float* og = out + (size_t)T * (ROWS_PER_BLOCK * 64);
    #pragma unroll
    for (int m = 0; m < 2; ++m) {
        int row = r0 + m;
        float o1[4], o2[4];
        #pragma unroll
        for (int d = 0; d < 4; ++d) {
            float a = acc[m][2 * d];       // even col -> x1
            float b = acc[m][2 * d + 1];   // odd col  -> x2
            o1[d] = a * cs4[d] - b * sn4[d];
            o2[d] = a * sn4[d] + b * cs4[d];
        }
        *(float4*)&og[row * 64 + cg * 4]      = make_float4(o1[0], o1[1], o1[2], o1[3]);
        *(float4*)&og[row * 64 + 32 + cg * 4] = make_float4(o2[0], o2[1], o2[2], o2[3]);
    }
}

extern "C" void kernel_launch(void* const* d_in, const int* in_sizes, int n_in,
                              void* d_out, int out_size, void* d_ws, size_t ws_size,
                              hipStream_t stream) {
    const float* x           = (const float*)d_in[0];
    const float* thetas      = (const float*)d_in[1];
    const float* theta_scale = (const float*)d_in[2];
    const float* r_matrix    = (const float*)d_in[3];
    const float* inv_freq    = (const float*)d_in[4];
    const int*   pairs       = (const int*)d_in[5];
    float*       out         = (float*)d_out;
    float*       W           = (float*)d_ws;   // 64*64 floats = 16 KB scratch

    build_w_kernel<<<16, 256, 0, stream>>>(thetas, theta_scale, r_matrix, pairs, W);
    rotary_main_kernel<<<NTILES, 256, 0, stream>>>(x, W, inv_freq, out);
}

// Round 7
// 106.113 us; speedup vs baseline: 1.1224x; 1.0287x over previous
//
#include <hip/hip_runtime.h>
#include <math.h>

// Problem constants
#define SEQ    2048
#define ROT    32
#define ROWS_PER_BLOCK 64
#define NTILES (131072 / ROWS_PER_BLOCK)   // 2048 blocks

#define AS1 __attribute__((address_space(1)))
#define AS3 __attribute__((address_space(3)))

// ---------------------------------------------------------------------------
// Setup kernel v3: W = 32 * (A @ r_matrix).
// Overlap trick: R is DMA'd into LDS via global_load_lds issued AFTER the
// first barrier, so the (cold, ~900cyc) R fetch runs concurrently with the
// 32-step sequential scan chain; the second barrier drains both.
// ---------------------------------------------------------------------------
__global__ __launch_bounds__(256) void build_w_kernel(
    const float* __restrict__ thetas,
    const float* __restrict__ theta_scale,
    const float* __restrict__ R,        // r_matrix, 64x64 row-major
    const int*   __restrict__ pairs,    // 32 x 2
    float*       __restrict__ W)        // out: 64x64 row-major
{
    __shared__ float A[64 * 65];        // +1 pad: conflict-free row reads
    __shared__ float Rs[64 * 64];       // R staged async, overlapped with scan
    __shared__ float Cs[ROT], Ss[ROT];
    __shared__ int   Pi[ROT], Pj[ROT];
    const int t    = threadIdx.x;
    const int wave = t >> 6;
    const int lane = t & 63;

    #pragma unroll
    for (int i = 0; i < 16; ++i) {
        int e = i * 256 + t;
        int r = e >> 6, c = e & 63;
        A[r * 65 + c] = (r == c) ? 1.0f : 0.0f;
    }
    if (t < ROT) {                      // precompute rotation params
        float th = thetas[t] * theta_scale[0];
        float sv, cv;
        sincosf(th, &sv, &cv);
        Cs[t] = cv; Ss[t] = sv;
        Pi[t] = pairs[2 * t]; Pj[t] = pairs[2 * t + 1];
    }
    __syncthreads();                    // A init + params visible

    // ---- issue async R staging NOW: DMA overlaps the scan below ----
    #pragma unroll
    for (int i = 0; i < 4; ++i) {
        int ri  = i * 4 + wave;              // region 0..15 -> rows 4ri..4ri+3
        int row = ri * 4 + (lane >> 4);
        const float* gp = R + row * 64 + (lane & 15) * 4;
        __builtin_amdgcn_global_load_lds((const AS1 unsigned int*)gp,
                                         (AS3 unsigned int*)&Rs[ri * 256], 16, 0, 0);
    }

    if (t < 64) {                       // 32-step sequential scan, pure LDS
        float* Ar = &A[t * 65];
        for (int k = 0; k < ROT; ++k) {
            int i = Pi[k], j = Pj[k];
            float c = Cs[k], s = Ss[k];
            float ai = Ar[i], aj = Ar[j];
            if (i != j) { Ar[i] = c * ai + s * aj; Ar[j] = c * aj - s * ai; }
            else        { Ar[i] = s * ai; }   // ref: set(ni) overwritten by set(nj)=xi*s
        }
    }
    __syncthreads();                    // drains R DMA + scan writes

    const int r = (blockIdx.x << 2) + (t >> 6);   // 16 blocks * 4 rows
    const int c = t & 63;
    const float* Ar = &A[r * 65];                  // wave-uniform -> broadcast
    float acc = 0.0f;
    #pragma unroll 8
    for (int k = 0; k < 64; ++k)
        acc = fmaf(Ar[k], Rs[k * 64 + c], acc);    // lane=c stride-1: 2-way, free
    W[r * 64 + c] = 32.0f * acc;                   // fold *sqrt(1024)
}

// ---------------------------------------------------------------------------
// Main kernel v4: 64 rows/block, 2048 blocks, 256 threads, ~17 KB LDS.
// X read directly from global (no LDS staging); W LDS-staged via
// global_load_lds. New in v4: kk=0 X float4 pair is prefetched into VGPRs
// BEFORE the barrier (X and W latencies overlap, both drained by the same
// barrier), and the k-loop software-pipelines the next-kk X loads.
// ---------------------------------------------------------------------------
__global__ __launch_bounds__(256) void rotary_main_kernel(
    const float* __restrict__ x,
    const float* __restrict__ W,
    const float* __restrict__ inv_freq,
    float*       __restrict__ out)
{
    __shared__ float Ws[64 * 64];      // 16 KB, row-major
    __shared__ float SCc[4 * 32];      // cos per (pos-group, d)
    __shared__ float SCs[4 * 32];      // sin per (pos-group, d)

    const int T    = blockIdx.x;
    const int t    = threadIdx.x;
    const int wave = t >> 6;
    const int lane = t & 63;

    // ---- issue async W staging first ----
    #pragma unroll
    for (int i = 0; i < 4; ++i) {
        int ri  = i * 4 + wave;              // region 0..15 -> rows 4ri..4ri+3
        int row = ri * 4 + (lane >> 4);
        const float* gp = W + row * 64 + (lane & 15) * 4;
        __builtin_amdgcn_global_load_lds((const AS1 unsigned int*)gp,
                                         (AS3 unsigned int*)&Ws[ri * 256], 16, 0, 0);
    }
    // ---- sincos for the 4 positions covered by this tile (VALU, overlaps) ----
    if (t < 128) {
        int pg = t >> 5, d = t & 31;
        int pos = (T * 4 + pg) & (SEQ - 1);  // position = global_row/16 mod SEQ
        float sv, cv;
        sincosf((float)pos * inv_freq[d], &sv, &cv);
        SCc[t] = cv;
        SCs[t] = sv;
    }

    // ---- prefetch kk=0 X into VGPRs BEFORE the barrier ----
    const int rp = t >> 3;             // 0..31 -> rows 2rp, 2rp+1
    const int cg = t & 7;              // 0..7
    const int r0 = rp * 2;
    const float* xr0 = x + (size_t)T * (ROWS_PER_BLOCK * 64) + r0 * 64;
    const float* xr1 = xr0 + 64;
    float4 nx0 = *(const float4*)(xr0);
    float4 nx1 = *(const float4*)(xr1);

    __syncthreads();                   // drains W DMA (and X prefetch)

    float acc[2][8];
    #pragma unroll
    for (int m = 0; m < 2; ++m)
        #pragma unroll
        for (int j = 0; j < 8; ++j) acc[m][j] = 0.0f;

    #pragma unroll 4
    for (int kk = 0; kk < 16; ++kk) {  // 4 k per iteration, X pipelined
        const float4 xv0 = nx0;
        const float4 xv1 = nx1;
        if (kk < 15) {                 // issue next-kk loads ahead of the FMAs
            nx0 = *(const float4*)(xr0 + ((kk + 1) << 2));
            nx1 = *(const float4*)(xr1 + ((kk + 1) << 2));
        }
        float4 wv[8];
        #pragma unroll
        for (int r = 0; r < 4; ++r) {
            wv[2 * r]     = *(const float4*)&Ws[(4 * kk + r) * 64 + cg * 8];
            wv[2 * r + 1] = *(const float4*)&Ws[(4 * kk + r) * 64 + cg * 8 + 4];
        }
        const float xa[2][4] = {{xv0.x, xv0.y, xv0.z, xv0.w},
                                {xv1.x, xv1.y, xv1.z, xv1.w}};
        #pragma unroll
        for (int m = 0; m < 2; ++m)
            #pragma unroll
            for (int r = 0; r < 4; ++r) {
                const float4 w0 = wv[2 * r], w1 = wv[2 * r + 1];
                const float xs = xa[m][r];
                acc[m][0] = fmaf(xs, w0.x, acc[m][0]);
                acc[m][1] = fmaf(xs, w0.y, acc[m][1]);
                acc[m][2] = fmaf(xs, w0.z, acc[m][2]);
                acc[m][3] = fmaf(xs, w0.w, acc[m][3]);
                acc[m][4] = fmaf(xs, w1.x, acc[m][4]);
                acc[m][5] = fmaf(xs, w1.y, acc[m][5]);
                acc[m][6] = fmaf(xs, w1.z, acc[m][6]);
                acc[m][7] = fmaf(xs, w1.w, acc[m][7]);
            }
    }

    // ---- RoPE epilogue in registers; coalesced 16B stores ----
    const int scb = (r0 >> 4) * 32 + cg * 4;   // pos-group (r0 even: rows never
    const float4 cv = *(const float4*)&SCc[scb];  // cross a 16-row boundary)
    const float4 sv = *(const float4*)&SCs[scb];
    const float cs4[4] = {cv.x, cv.y, cv.z, cv.w};
    const float sn4[4] = {sv.x, sv.y, sv.z, sv.w};

    float* og = out + (size_t)T * (ROWS_PER_BLOCK * 64);
    #pragma unroll
    for (int m = 0; m < 2; ++m) {
        int row = r0 + m;
        float o1[4], o2[4];
        #pragma unroll
        for (int d = 0; d < 4; ++d) {
            float a = acc[m][2 * d];       // even col -> x1
            float b = acc[m][2 * d + 1];   // odd col  -> x2
            o1[d] = a * cs4[d] - b * sn4[d];
            o2[d] = a * sn4[d] + b * cs4[d];
        }
        *(float4*)&og[row * 64 + cg * 4]      = make_float4(o1[0], o1[1], o1[2], o1[3]);
        *(float4*)&og[row * 64 + 32 + cg * 4] = make_float4(o2[0], o2[1], o2[2], o2[3]);
    }
}

extern "C" void kernel_launch(void* const* d_in, const int* in_sizes, int n_in,
                              void* d_out, int out_size, void* d_ws, size_t ws_size,
                              hipStream_t stream) {
    const float* x           = (const float*)d_in[0];
    const float* thetas      = (const float*)d_in[1];
    const float* theta_scale = (const float*)d_in[2];
    const float* r_matrix    = (const float*)d_in[3];
    const float* inv_freq    = (const float*)d_in[4];
    const int*   pairs       = (const int*)d_in[5];
    float*       out         = (float*)d_out;
    float*       W           = (float*)d_ws;   // 64*64 floats = 16 KB scratch

    build_w_kernel<<<16, 256, 0, stream>>>(thetas, theta_scale, r_matrix, pairs, W);
    rotary_main_kernel<<<NTILES, 256, 0, stream>>>(x, W, inv_freq, out);
}